// Round 12
// baseline (346.084 us; speedup 1.0000x reference)
//
#include <hip/hip_runtime.h>
#include <hip/hip_cooperative_groups.h>
#include <cmath>

namespace cg = cooperative_groups;

// ---------------------------------------------------------------------------
// Bit-exact replication of the reference's f32 cumsum TREE (JAX associative
// scan), validated rounds 5-11 (absmax 1.831e-3 — bf16-quantized compare;
// non-chaotic-path deltas <1e-6 are free).
// Round 18 (WIN, 136.7us) / Round 22 (WIN, 135.9us): S-interface + 12KB
//   pair-swizzle scan. Budget: f0up ~8 + scan ~34 + synth 50.2 + ~44us of
//   inter-dispatch gaps (~14.6us x 3) — the gaps are now the biggest
//   attackable item (two rounds of scan4 surgery moved total by ~1us).
// Round 23: ONE cooperative dispatch (guide-sanctioned
//   hipLaunchCooperativeKernel) with two grid.sync()s:
//   phase A = f0up+zero (verbatim expressions), phase B = r22 scan body,
//   phase C = r18/r22 synth body (LDS carved from the shared 12KB buffer).
//   Grid = occupancy-API blocks/SM x numCU (co-residency guaranteed).
//   All numeric DAGs byte-identical — only who/when computes changes.
//   SAFETY: if hipLaunchCooperativeKernel errors (capture incompat), fall
//   back inline to the proven r22 3-dispatch path.
// ---------------------------------------------------------------------------
#pragma clang fp contract(off)

#define SRF   48000.0f
#define NYQF  21600.0f                    // fp32(48000*0.45), exact
constexpr float  TWO_PI_F  = 6.283185307179586476925286766559f;  // 0x40C90FDB
constexpr double INV_2PI_D = 0.15915494309189533576888376337251;
constexpr float  RC1 = (float)INV_2PI_D;
constexpr float  RC2 = (float)(INV_2PI_D - (double)RC1);
constexpr double INV_SR_D = 1.0 / 48000.0;
constexpr float  DD1 = (float)INV_SR_D;
constexpr float  DD2 = (float)(INV_SR_D - (double)DD1);

__device__ __forceinline__ float hsin_rev(float r) {  // sin(2*pi*r)
#if __has_builtin(__builtin_amdgcn_sinf)
    return __builtin_amdgcn_sinf(r);                  // v_sin_f32: revolutions
#else
    return __sinf(r * TWO_PI_F);
#endif
}

// Correctly-rounded t/48000 via double-float mul (== IEEE f32 divide here;
// proved: no halfway cases, err 2^-47 << 2^-33.5 boundary distance).
__device__ __forceinline__ float div48000(float t) {
    float h = t * DD1;
    float r = __builtin_fmaf(t, DD1, -h);
    float s = __builtin_fmaf(t, DD2, r);
    return h + s;
}

// sin(ph) for f32 ph: double-float reduction to revolutions (|err|<=2^-25 rev)
__device__ __forceinline__ float sin_phase(float ph) {
    float h  = ph * RC1;
    float r  = __builtin_fmaf(ph, RC1, -h);
    float s  = __builtin_fmaf(ph, RC2, r);
    float nn = __builtin_rintf(h);
    float fr = (h - nn) + s;
    return hsin_rev(fr);
}

// group-of-4 broadcast: value of lane (lane&~3)+idx  (idx=0..3 static)
template <int IDX>
__device__ __forceinline__ float grp4_bcast(float v, int lb) {
#if __has_builtin(__builtin_amdgcn_ds_swizzle)
    constexpr int imm = (IDX << 5) | 0x1C;
    return __int_as_float(__builtin_amdgcn_ds_swizzle(__float_as_int(v), imm));
#else
    return __shfl(v, lb + IDX);
#endif
}

// group-of-8 broadcast: value of lane (lane&~7)
__device__ __forceinline__ float grp8_bcast0(float v, int lane) {
#if __has_builtin(__builtin_amdgcn_ds_swizzle)
    return __int_as_float(__builtin_amdgcn_ds_swizzle(__float_as_int(v), 0x0018));
#else
    return __shfl(v, lane & ~7);
#endif
}

// lane-pair swap: exchange values of lanes 2m <-> 2m+1 (xor 1)
__device__ __forceinline__ float pair_swap(float v) {
#if __has_builtin(__builtin_amdgcn_ds_swizzle)
    return __int_as_float(__builtin_amdgcn_ds_swizzle(__float_as_int(v), 0x041F));
#else
    return __shfl_xor(v, 1);
#endif
}

// kc[b,k] = fp32(k * fp32(sqrt(fp32(1 + fp32(inh*k^2)))))  -- np/jnp-exact
__device__ __forceinline__ float kcval(int k, float ib) {
    float kf = (float)(k + 1);
    float k2 = kf * kf;
    float m  = ib * k2;
    float s1 = 1.0f + m;
    float st = (float)sqrt((double)s1);
    return kf * st;
}

// ---- Fused cooperative kernel: phaseA f0up+zero / sync / scan / sync / synth
__global__ void __launch_bounds__(256) k_fused(
        const float* __restrict__ harm, const float* __restrict__ f0,
        const float* __restrict__ inh,  float* __restrict__ f0up,
        float* __restrict__ scanS,      float* __restrict__ out,
        int B, int T, int N, int n, float pf, int kpg, int tiles, int KZ) {
    cg::grid_group gridg = cg::this_grid();
    __shared__ float lv[3008];                 // 12KB: scan levels / synth bufs
    const int tid = threadIdx.x;
    const int G   = gridDim.x;
    const float tmaxf = (float)(T - 1);
    const int len4 = n >> 4;
    const int len5 = n >> 5;
    const int NG   = n >> 4;
    const int NG5P = (n >> 5) + 1;

    // ---- Phase A: f0up interp (k_f0up expression verbatim) + out zero ----
    {
        const long total = (long)B * n;
        for (long idx = (long)blockIdx.x * 256 + tid; idx < total;
             idx += (long)G * 256) {
            int b = (int)(idx / n);
            int j = (int)(idx - (long)b * n);
            float pos = ((float)j + 0.5f);
            pos = pos * pf;
            pos = pos - 0.5f;
            pos = fmaxf(pos, 0.0f);
            pos = fminf(pos, tmaxf);
            int   i0 = (int)pos;
            int   i1 = min(i0 + 1, T - 1);
            float w  = pos - (float)i0;
            float omw = 1.0f - w;
            const float* fb = f0 + b * T;
            f0up[idx] = fb[i0] * omw + fb[i1] * w;
            out[idx]  = 0.0f;
        }
    }
    gridg.sync();

    // ---- Phase B: r22-validated scan body, grid-stride over (k,b) --------
    for (int vb = blockIdx.x; vb < N * B; vb += G) {
        const int k = vb % N;
        const int b = vb / N;
        const float kc = kcval(k, inh[b]);
        const float4* f4 = (const float4*)(f0up + (size_t)b * n);

        auto l2of = [&](float4 v) -> float {
            float a0 = div48000(TWO_PI_F * (kc * v.x));
            float a1 = div48000(TWO_PI_F * (kc * v.y));
            float a2 = div48000(TWO_PI_F * (kc * v.z));
            float a3 = div48000(TWO_PI_F * (kc * v.w));
            return (a0 + a1) + (a2 + a3);
        };
        auto l4of = [&](int j) -> float {      // L4 leaf j — r14-validated DAG
            float s01 = l2of(f4[4*j])     + l2of(f4[4*j + 1]);
            float s23 = l2of(f4[4*j + 2]) + l2of(f4[4*j + 3]);
            return s01 + s23;
        };
        for (int i = tid; i < len4; i += 256) {
            float v  = l4of(i);
            float vp = pair_swap(v);
            if ((i & 1) == 0) lv[i >> 1] = v + vp;   // L5[i] (r17 bracketing)
        }
        __syncthreads();

        int offp = 0, lenp = len5, P = 5;
        for (int l = 6; ; ++l) {
            int lenc = lenp >> 1;
            int offc = offp + lenp;
            for (int i = tid; i < lenc; i += 256)
                lv[offc + i] = lv[offp + 2*i] + lv[offp + 2*i + 1];
            __syncthreads();
            P = l;
            if (lenc == 1) break;
            offp = offc; lenp = lenc;
        }
        for (int l = P - 1; l >= 5; --l) {
            int lenl = n >> l;
            int offl = 0;
            for (int m = 5; m < l; ++m) offl += (n >> m);
            float*       arr = lv + offl;
            const float* hi  = lv + offl + lenl;
            int lenh = n >> (l + 1);
            for (int i = tid; i < lenh; i += 256) {
                float v = hi[i];
                int e = 2*i + 2;
                if (e < lenl) arr[e] = v + arr[e];
                arr[2*i + 1] = v;
            }
            __syncthreads();
        }
        float* sp = scanS + (size_t)(b * N + k) * (len5 + 1);
        if (tid == 0) sp[0] = 0.0f;
        for (int i = tid; i < len5; i += 256) sp[1 + i] = lv[i];
        __syncthreads();                       // protect lv before next vb
    }
    gridg.sync();

    // ---- Phase C: r18/r22-validated synth body, grid-stride over tiles ---
    // LDS carve: amps = lv[0..511] (float2[256]); kcs = lv[512..543];
    // xp = lv[544..1567] (4 waves x 256 floats; 16B-aligned base).
    float2* amps = (float2*)lv;
    float*  kcs  = lv + 512;
    float*  xp   = lv + 544;
    const int totC = tiles * B * KZ;
    const int lane = tid & 63;
    const int lb   = lane & ~3;

    for (int vs = blockIdx.x; vs < totC; vs += G) {
        const int tile = vs % tiles;
        const int rb   = vs / tiles;
        const int b    = rb % B;
        const int z    = rb / B;
        const int k0   = z * kpg;
        const int g2   = tile * 256 + tid;
        const int q    = g2 >> 2;
        const int c    = g2 & 3;
        const int kend = min(k0 + kpg, N);
        const int kact = kend - k0;
        const bool valid = q < NG;
        const bool oddq  = (q & 1) != 0;
        const int  si    = (q >> 1) + (q & 1);

        const float ib = inh[b];
        for (int i = tid; i < kact; i += 256) kcs[i] = kcval(k0 + i, ib);

        const int j0blk = tile * 1024;
        int i0min;
        {
            float p = ((float)j0blk + 0.5f);
            p = p * pf; p = p - 0.5f;
            p = fmaxf(p, 0.0f); p = fminf(p, tmaxf);
            i0min = (int)p;
        }
        for (int idx = tid; idx < 8 * kact; idx += 256) {
            int r = idx / kact, kk = idx - r * kact;
            int r0 = min(i0min + r, T - 1);
            int r1 = min(i0min + r + 1, T - 1);
            float a0 = harm[((size_t)b * T + r0) * N + (k0 + kk)];
            float a1 = harm[((size_t)b * T + r1) * N + (k0 + kk)];
            amps[idx] = make_float2(a0, a1 - a0);
        }
        __syncthreads();

        float u0=0.f,u1=0.f,u2=0.f,u3=0.f;
        float w0=0.f,w1=0.f,w2=0.f,w3=0.f;
        int   a0o=0,a1o=0,a2o=0,a3o=0;
        float acc0=0.f, acc1=0.f, acc2=0.f, acc3=0.f;
        float um = __builtin_inff();
        if (valid) {
            const float4 v = *(const float4*)(f0up + (size_t)b * n + (size_t)q * 16 + c * 4);
            u0=v.x; u1=v.y; u2=v.z; u3=v.w;
            um = fminf(fminf(u0,u1), fminf(u2,u3));
            const int jb = q * 16 + c * 4;
            #pragma unroll
            for (int i = 0; i < 4; ++i) {
                float p = ((float)(jb + i) + 0.5f);
                p = p * pf; p = p - 0.5f;
                p = fmaxf(p, 0.0f); p = fminf(p, tmaxf);
                int i0 = (int)p;
                float wv = p - (float)i0;
                int aoo  = (i0 - i0min) * kact;
                if (i==0){w0=wv;a0o=aoo;}
                else if (i==1){w1=wv;a1o=aoo;}
                else if (i==2){w2=wv;a2o=aoo;}
                else {w3=wv;a3o=aoo;}
            }
        }
        #pragma unroll
        for (int off = 32; off > 0; off >>= 1)
            um = fminf(um, __shfl_xor(um, off));
        const float umin = um;

        if (valid) {
            const float* s4k = scanS + (size_t)(b * N + k0) * NG5P;
            float svc = s4k[si];

            for (int k = k0; k < kend; ++k) {
                const int   kk = k - k0;
                const float kc = kcs[kk];
                if (kc * umin >= NYQF) break;
                const float Sv = svc;
                if (k + 1 < kend) {
                    const float* nx = s4k + NG5P;
                    svc = nx[si];
                    s4k = nx;
                }

                float x0 = div48000(TWO_PI_F * (kc * u0));
                float x1 = div48000(TWO_PI_F * (kc * u1));
                float x2 = div48000(TWO_PI_F * (kc * u2));
                float x3 = div48000(TWO_PI_F * (kc * u3));
                float L1p = x0 + x1, L1q = x2 + x3;
                float L2  = L1p + L1q;

                float s0 = grp4_bcast<0>(L2, lb);
                float s1 = grp4_bcast<1>(L2, lb);
                float s2 = grp4_bcast<2>(L2, lb);
                float s3 = grp4_bcast<3>(L2, lb);
                float t01 = s0 + s1;
                float s23 = s2 + s3;
                float L4v = t01 + s23;           // == l4of bracketing
                float G1e = Sv + L4v;            // fl(S[i]+L4[2i]) on even q
                float Gx  = grp8_bcast0(G1e, lane);
                float G0  = oddq ? Gx : Sv;
                float G1  = oddq ? Sv : G1e;

                float b1v = G0 + s0;
                float b2v = G0 + t01;
                float b3v = b2v + s2;
                float base = (c == 0) ? G0  : (c == 1) ? b1v : (c == 2) ? b2v : b3v;
                float bn   = (c == 0) ? b1v : (c == 1) ? b2v : (c == 2) ? b3v : G1;

                float ph0 = base + x0;
                float ph1 = base + L1p;
                float ph2 = ph1 + x2;
                float ph3 = bn;

                {   float t1 = kc * u0;
                    if (t1 < NYQF) { float sv = sin_phase(ph0);
                        float2 a = amps[a0o + kk];
                        acc0 = __builtin_fmaf(__builtin_fmaf(w0, a.y, a.x), sv, acc0); } }
                {   float t1 = kc * u1;
                    if (t1 < NYQF) { float sv = sin_phase(ph1);
                        float2 a = amps[a1o + kk];
                        acc1 = __builtin_fmaf(__builtin_fmaf(w1, a.y, a.x), sv, acc1); } }
                {   float t1 = kc * u2;
                    if (t1 < NYQF) { float sv = sin_phase(ph2);
                        float2 a = amps[a2o + kk];
                        acc2 = __builtin_fmaf(__builtin_fmaf(w2, a.y, a.x), sv, acc2); } }
                {   float t1 = kc * u3;
                    if (t1 < NYQF) { float sv = sin_phase(ph3);
                        float2 a = amps[a3o + kk];
                        acc3 = __builtin_fmaf(__builtin_fmaf(w3, a.y, a.x), sv, acc3); } }
            }
        }

        // wave-local transpose epilogue (r14-validated)
        {
            const int wid = tid >> 6;
            *(float4*)&xp[wid * 256 + 4 * lane] = make_float4(acc0, acc1, acc2, acc3);
            const float Nf = (float)N;
            const int jb = tile * 1024 + wid * 256;
            float* ob = out + (size_t)b * n + jb;
            #pragma unroll
            for (int i = 0; i < 4; ++i) {
                float v  = xp[wid * 256 + i * 64 + lane];
                int   jj = jb + i * 64 + lane;
                if (jj < n) atomicAdd(&ob[i * 64 + lane], v / Nf);
            }
        }
        __syncthreads();                       // protect amps/xp for next vs
    }
}

// ---- K1: f0_up[b,j] (np-exact fp32 interp) + zero-init of out --------------
__global__ void __launch_bounds__(256) k_f0up(const float* __restrict__ f0,
        float* __restrict__ f0up, float* __restrict__ out,
        int T, int n, float pf) {
    int j = blockIdx.x * 256 + threadIdx.x;
    int b = blockIdx.y;
    if (j >= n) return;
    float pos = ((float)j + 0.5f);
    pos = pos * pf;
    pos = pos - 0.5f;
    pos = fmaxf(pos, 0.0f);
    pos = fminf(pos, (float)(T - 1));
    int   i0 = (int)pos;
    int   i1 = min(i0 + 1, T - 1);
    float w  = pos - (float)i0;
    float omw = 1.0f - w;
    const float* fb = f0 + b * T;
    f0up[(size_t)b * n + j] = fb[i0] * omw + fb[i1] * w;
    out[(size_t)b * n + j]  = 0.0f;            // harness poisons out; we own it
}

// ---- K2a: per (b,k) L5 scan from f0up; L4 via lane-pair swizzle (12KB) -----
__global__ void __launch_bounds__(256) k_scan4(const float* __restrict__ f0up,
        const float* __restrict__ inh, float* __restrict__ scanS,
        int N, int n) {
    __shared__ float lv[3008];
    const int k   = blockIdx.x;
    const int b   = blockIdx.y;
    const int tid = threadIdx.x;
    const float kc = kcval(k, inh[b]);
    const float4* f4 = (const float4*)(f0up + (size_t)b * n);
    const int len4 = n >> 4;
    const int len5 = n >> 5;

    auto l2of = [&](float4 v) -> float {
        float a0 = div48000(TWO_PI_F * (kc * v.x));
        float a1 = div48000(TWO_PI_F * (kc * v.y));
        float a2 = div48000(TWO_PI_F * (kc * v.z));
        float a3 = div48000(TWO_PI_F * (kc * v.w));
        return (a0 + a1) + (a2 + a3);
    };
    auto l4of = [&](int j) -> float {
        float s01 = l2of(f4[4*j])     + l2of(f4[4*j + 1]);
        float s23 = l2of(f4[4*j + 2]) + l2of(f4[4*j + 3]);
        return s01 + s23;
    };
    for (int i = tid; i < len4; i += 256) {
        float v  = l4of(i);
        float vp = pair_swap(v);
        if ((i & 1) == 0) lv[i >> 1] = v + vp;
    }
    __syncthreads();

    int offp = 0, lenp = len5, P = 5;
    for (int l = 6; ; ++l) {
        int lenc = lenp >> 1;
        int offc = offp + lenp;
        for (int i = tid; i < lenc; i += 256)
            lv[offc + i] = lv[offp + 2*i] + lv[offp + 2*i + 1];
        __syncthreads();
        P = l;
        if (lenc == 1) break;
        offp = offc; lenp = lenc;
    }
    for (int l = P - 1; l >= 5; --l) {
        int lenl = n >> l;
        int offl = 0;
        for (int m = 5; m < l; ++m) offl += (n >> m);
        float*       arr = lv + offl;
        const float* hi  = lv + offl + lenl;
        int lenh = n >> (l + 1);
        for (int i = tid; i < lenh; i += 256) {
            float v = hi[i];
            int e = 2*i + 2;
            if (e < lenl) arr[e] = v + arr[e];
            arr[2*i + 1] = v;
        }
        __syncthreads();
    }
    float* sp = scanS + (size_t)(b * N + k) * (len5 + 1);
    if (tid == 0) sp[0] = 0.0f;
    for (int i = tid; i < len5; i += 256) sp[1 + i] = lv[i];
}

// ---- K2b: 4 lanes per 16-j group (byte-exact round-18 body) ----------------
__global__ void __launch_bounds__(256) k_synth4(
        const float* __restrict__ harm, const float* __restrict__ f0up,
        const float* __restrict__ inh,  const float* __restrict__ scanS,
        float* __restrict__ out, int B, int T, int N, int n, float pf, int kpg) {
    const int tid  = threadIdx.x;
    const int b    = blockIdx.y;
    const int k0   = blockIdx.z * kpg;
    const int g    = blockIdx.x * 256 + tid;
    const int q    = g >> 2;
    const int c    = g & 3;
    const int NG   = n >> 4;
    const int NG5P = (n >> 5) + 1;
    const int kend = min(k0 + kpg, N);
    const int kact = kend - k0;
    const bool valid = q < NG;
    const bool oddq  = (q & 1) != 0;
    const int  si    = (q >> 1) + (q & 1);

    __shared__ float2 amps[8 * 32];
    __shared__ float  kcs[32];
    __shared__ float  xp[4][256];

    const float ib    = inh[b];
    const float tmaxf = (float)(T - 1);
    for (int i = tid; i < kact; i += 256) kcs[i] = kcval(k0 + i, ib);

    const int j0blk = blockIdx.x * 1024;
    int i0min;
    {
        float p = ((float)j0blk + 0.5f);
        p = p * pf; p = p - 0.5f;
        p = fmaxf(p, 0.0f); p = fminf(p, tmaxf);
        i0min = (int)p;
    }
    for (int idx = tid; idx < 8 * kact; idx += 256) {
        int r = idx / kact, kk = idx - r * kact;
        int r0 = min(i0min + r, T - 1);
        int r1 = min(i0min + r + 1, T - 1);
        float a0 = harm[((size_t)b * T + r0) * N + (k0 + kk)];
        float a1 = harm[((size_t)b * T + r1) * N + (k0 + kk)];
        amps[idx] = make_float2(a0, a1 - a0);
    }
    __syncthreads();

    float u0=0.f,u1=0.f,u2=0.f,u3=0.f;
    float w0=0.f,w1=0.f,w2=0.f,w3=0.f;
    int   a0o=0,a1o=0,a2o=0,a3o=0;
    float acc0=0.f, acc1=0.f, acc2=0.f, acc3=0.f;
    float um = __builtin_inff();
    if (valid) {
        const float4 v = *(const float4*)(f0up + (size_t)b * n + (size_t)q * 16 + c * 4);
        u0=v.x; u1=v.y; u2=v.z; u3=v.w;
        um = fminf(fminf(u0,u1), fminf(u2,u3));
        const int jb = q * 16 + c * 4;
        #pragma unroll
        for (int i = 0; i < 4; ++i) {
            float p = ((float)(jb + i) + 0.5f);
            p = p * pf; p = p - 0.5f;
            p = fmaxf(p, 0.0f); p = fminf(p, tmaxf);
            int i0 = (int)p;
            float wv = p - (float)i0;
            int aoo  = (i0 - i0min) * kact;
            if (i==0){w0=wv;a0o=aoo;}
            else if (i==1){w1=wv;a1o=aoo;}
            else if (i==2){w2=wv;a2o=aoo;}
            else {w3=wv;a3o=aoo;}
        }
    }
    #pragma unroll
    for (int off = 32; off > 0; off >>= 1)
        um = fminf(um, __shfl_xor(um, off));
    const float umin = um;
    const int lane = tid & 63;
    const int lb   = lane & ~3;

    if (valid) {
        const float* s4k = scanS + (size_t)(b * N + k0) * NG5P;
        float svc = s4k[si];

        for (int k = k0; k < kend; ++k) {
            const int   kk = k - k0;
            const float kc = kcs[kk];
            if (kc * umin >= NYQF) break;
            const float Sv = svc;
            if (k + 1 < kend) {
                const float* nx = s4k + NG5P;
                svc = nx[si];
                s4k = nx;
            }

            float x0 = div48000(TWO_PI_F * (kc * u0));
            float x1 = div48000(TWO_PI_F * (kc * u1));
            float x2 = div48000(TWO_PI_F * (kc * u2));
            float x3 = div48000(TWO_PI_F * (kc * u3));
            float L1p = x0 + x1, L1q = x2 + x3;
            float L2  = L1p + L1q;

            float s0 = grp4_bcast<0>(L2, lb);
            float s1 = grp4_bcast<1>(L2, lb);
            float s2 = grp4_bcast<2>(L2, lb);
            float s3 = grp4_bcast<3>(L2, lb);
            float t01 = s0 + s1;
            float s23 = s2 + s3;
            float L4v = t01 + s23;
            float G1e = Sv + L4v;
            float Gx  = grp8_bcast0(G1e, lane);
            float G0  = oddq ? Gx : Sv;
            float G1  = oddq ? Sv : G1e;

            float b1v = G0 + s0;
            float b2v = G0 + t01;
            float b3v = b2v + s2;
            float base = (c == 0) ? G0  : (c == 1) ? b1v : (c == 2) ? b2v : b3v;
            float bn   = (c == 0) ? b1v : (c == 1) ? b2v : (c == 2) ? b3v : G1;

            float ph0 = base + x0;
            float ph1 = base + L1p;
            float ph2 = ph1 + x2;
            float ph3 = bn;

            {   float t1 = kc * u0;
                if (t1 < NYQF) { float sv = sin_phase(ph0);
                    float2 a = amps[a0o + kk];
                    acc0 = __builtin_fmaf(__builtin_fmaf(w0, a.y, a.x), sv, acc0); } }
            {   float t1 = kc * u1;
                if (t1 < NYQF) { float sv = sin_phase(ph1);
                    float2 a = amps[a1o + kk];
                    acc1 = __builtin_fmaf(__builtin_fmaf(w1, a.y, a.x), sv, acc1); } }
            {   float t1 = kc * u2;
                if (t1 < NYQF) { float sv = sin_phase(ph2);
                    float2 a = amps[a2o + kk];
                    acc2 = __builtin_fmaf(__builtin_fmaf(w2, a.y, a.x), sv, acc2); } }
            {   float t1 = kc * u3;
                if (t1 < NYQF) { float sv = sin_phase(ph3);
                    float2 a = amps[a3o + kk];
                    acc3 = __builtin_fmaf(__builtin_fmaf(w3, a.y, a.x), sv, acc3); } }
        }
    }

    {
        const int wid  = tid >> 6;
        *(float4*)&xp[wid][4 * lane] = make_float4(acc0, acc1, acc2, acc3);
        const float Nf = (float)N;
        const int jb = blockIdx.x * 1024 + wid * 256;
        float* ob = out + (size_t)b * n + jb;
        #pragma unroll
        for (int i = 0; i < 4; ++i) {
            float v  = xp[wid][i * 64 + lane];
            int   jj = jb + i * 64 + lane;
            if (jj < n) atomicAdd(&ob[i * 64 + lane], v / Nf);
        }
    }
}

// ---- Fallback: round-5 proven kernel (atomics, 96 KB LDS) ------------------
__global__ void __launch_bounds__(256) k_scan_synth(
        const float* __restrict__ harm, const float* __restrict__ f0up,
        const float* __restrict__ inh,  float* __restrict__ out,
        int B, int T, int N, int n, float pf) {
    extern __shared__ float lv[];
    const int k   = blockIdx.x;
    const int b   = blockIdx.y;
    const int tid = threadIdx.x;
    const float kc = kcval(k, inh[b]);
    const float* fb = f0up + (size_t)b * n;

    auto inc = [&](int j) -> float {
        float u    = fb[j];
        float inst = kc * u;
        float tt   = TWO_PI_F * inst;
        return tt / SRF;
    };

    const int len1 = n >> 1;
    {
        const float4* f4 = (const float4*)fb;
        for (int i = tid; i < (n >> 2); i += 256) {
            float4 u = f4[i];
            float a0 = (TWO_PI_F * (kc * u.x)) / SRF;
            float a1 = (TWO_PI_F * (kc * u.y)) / SRF;
            float a2 = (TWO_PI_F * (kc * u.z)) / SRF;
            float a3 = (TWO_PI_F * (kc * u.w)) / SRF;
            lv[i] = (a0 + a1) + (a2 + a3);
        }
    }
    __syncthreads();
    int offp = 0, lenp = n >> 2, P = 2;
    for (int l = 3; ; ++l) {
        int lenc = lenp >> 1;
        int offc = offp + lenp;
        for (int i = tid; i < lenc; i += 256)
            lv[offc + i] = lv[offp + 2*i] + lv[offp + 2*i + 1];
        __syncthreads();
        P = l;
        if (lenc == 1) break;
        offp = offc; lenp = lenc;
    }
    for (int l = P - 1; l >= 2; --l) {
        int lenl = n >> l;
        int offl = 0;
        for (int m = 2; m < l; ++m) offl += (n >> m);
        float*       arr = lv + offl;
        const float* hi  = lv + offl + lenl;
        int lenh = n >> (l + 1);
        for (int i = tid; i < lenh; i += 256) {
            float v = hi[i];
            int e = 2*i + 2;
            if (e < lenl) arr[e] = v + arr[e];
            arr[2*i + 1] = v;
        }
        __syncthreads();
    }
    const float* scan2 = lv;

    const float  tmaxf = (float)(T - 1);
    const float  invN  = 1.0f / (float)N;
    const float* hb    = harm + (size_t)b * T * N + k;
    float*       ob    = out + (size_t)b * n;

    auto emit = [&](int j, float ph) {
        float u    = fb[j];
        float inst = kc * u;
        if (!(inst < NYQF)) return;
        double pr = (double)ph * INV_2PI_D;
        double fr = pr - rint(pr);
        float  sv = hsin_rev((float)fr);
        float pos = ((float)j + 0.5f);
        pos = pos * pf; pos = pos - 0.5f;
        pos = fmaxf(pos, 0.0f); pos = fminf(pos, tmaxf);
        int   i0 = (int)pos;
        int   i1 = min(i0 + 1, T - 1);
        float w  = pos - (float)i0;
        float a  = hb[(size_t)i0 * N] * (1.0f - w) + hb[(size_t)i1 * N] * w;
        atomicAdd(&ob[j], (a * sv) * invN);
    };

    if (tid == 0) emit(0, inc(0));
    for (int tt = tid; tt < len1; tt += 256) {
        float s1;
        if (tt == 0)      s1 = inc(0) + inc(1);
        else if (tt & 1)  s1 = scan2[(tt - 1) >> 1];
        else              s1 = scan2[(tt >> 1) - 1] + (inc(2*tt) + inc(2*tt + 1));
        emit(2*tt + 1, s1);
        int je = 2*tt + 2;
        if (je < n) emit(je, s1 + inc(je));
    }
}

extern "C" void kernel_launch(void* const* d_in, const int* in_sizes, int n_in,
                              void* d_out, int out_size, void* d_ws, size_t ws_size,
                              hipStream_t stream) {
    const int B = in_sizes[2];                 // 16
    const int T = in_sizes[1] / B;             // 250
    const int N = in_sizes[0] / (B * T);       // 100
    const int n = out_size / B;                // 48000
    const float pf = (float)((double)T / (double)n);

    const float* harm = (const float*)d_in[0];
    const float* f0   = (const float*)d_in[1];
    const float* inh  = (const float*)d_in[2];
    float* out  = (float*)d_out;
    float* f0up = (float*)d_ws;                // B*n floats = 3.07 MB

    const int KZ  = 4;
    const int kpg = (N + KZ - 1) / KZ;         // 25
    const int NG  = n / 16;                    // 3000
    const int NG5 = n / 32;                    // 1500
    const int tiles = (NG * 4 + 255) / 256;    // 47
    const size_t needFast = (size_t)B * n * 4 + (size_t)B * N * (NG5 + 1) * 4;
    const bool fast = (ws_size >= needFast) && (n % 32 == 0) && (kpg <= 32);

    if (fast) {
        float* scanS = (float*)((char*)d_ws + (size_t)B * n * 4);

        // One-time device/occupancy query (host-side, no stream ops).
        static int s_G = -2;                   // -2 = uninitialized
        if (s_G == -2) {
            int dev = 0;
            (void)hipGetDevice(&dev);
            int coop = 0;
            (void)hipDeviceGetAttribute(&coop, hipDeviceAttributeCooperativeLaunch, dev);
            int numCU = 0;
            (void)hipDeviceGetAttribute(&numCU, hipDeviceAttributeMultiprocessorCount, dev);
            int bpc = 0;
            (void)hipOccupancyMaxActiveBlocksPerMultiprocessor(&bpc, k_fused, 256, 0);
            s_G = (coop && bpc > 0 && numCU > 0) ? bpc * numCU : 0;
        }

        bool done = false;
        if (s_G > 0) {
            const float* a_harm = harm; const float* a_f0 = f0;
            const float* a_inh = inh;   float* a_f0up = f0up;
            float* a_scanS = scanS;     float* a_out = out;
            int a_B = B, a_T = T, a_N = N, a_n = n;
            float a_pf = pf; int a_kpg = kpg, a_tiles = tiles, a_KZ = KZ;
            void* args[] = { (void*)&a_harm, (void*)&a_f0, (void*)&a_inh,
                             (void*)&a_f0up, (void*)&a_scanS, (void*)&a_out,
                             (void*)&a_B, (void*)&a_T, (void*)&a_N, (void*)&a_n,
                             (void*)&a_pf, (void*)&a_kpg, (void*)&a_tiles,
                             (void*)&a_KZ };
            hipError_t e = hipLaunchCooperativeKernel(k_fused, dim3(s_G),
                                                      dim3(256), args, 0, stream);
            if (e == hipSuccess) {
                done = true;
            } else {
                (void)hipGetLastError();       // clear; fall back below
                s_G = 0;                       // don't retry next calls
            }
        }
        if (!done) {
            // Proven r22 3-dispatch path.
            k_f0up<<<dim3((n + 255) / 256, B), 256, 0, stream>>>(f0, f0up, out, T, n, pf);
            k_scan4<<<dim3(N, B), 256, 0, stream>>>(f0up, inh, scanS, N, n);
            k_synth4<<<dim3(tiles, B, KZ), 256, 0, stream>>>(
                harm, f0up, inh, scanS, out, B, T, N, n, pf, kpg);
        }
    } else {
        k_f0up<<<dim3((n + 255) / 256, B), 256, 0, stream>>>(f0, f0up, out, T, n, pf);
        const size_t lds_bytes = (size_t)(n / 2) * sizeof(float);  // 96 KB
        k_scan_synth<<<dim3(N, B), 256, lds_bytes, stream>>>(
            harm, f0up, inh, out, B, T, N, n, pf);
    }
}

// Round 13
// 135.841 us; speedup vs baseline: 2.5477x; 2.5477x over previous
//
#include <hip/hip_runtime.h>
#include <cmath>

// ---------------------------------------------------------------------------
// Bit-exact replication of the reference's f32 cumsum TREE (JAX associative
// scan), validated rounds 5-11 (absmax 1.831e-3 — bf16-quantized compare;
// non-chaotic-path deltas <1e-6 are free).
// Round 18 (WIN, 136.7us) / Round 22 (WIN, 135.9us): S-interface + 12KB
//   pair-swizzle scan. Budget: f0up ~8 + scan ~34 + synth 50.2 + ~44us
//   dispatch gaps.
// Round 23 (REGRESSED 346us, reverted): cooperative single-dispatch fusion —
//   hipLaunchCooperativeKernel interacts pathologically with graph-capture
//   timing (rocprof 91s/run, parse fail). Dispatch gaps are harness-
//   structural; every fusion route (r16/r19/r23) lost more than it saved.
// Round 24: byte-exact r22 + ONE isolated change (from the r15 bundle,
//   where its WRITE drop 12000->11046KB was measured but attribution was
//   destroyed): wave-uniform dead-wave skip in synth4.
//   alive = (kcs[0]*umin < NYQF); kc monotone in k => first harmonic cut
//   => whole partition cut. Gates k-loop AND transpose epilogue (those
//   waves only atomicAdd zeros). Wave-uniform branch, no DAG change.
// ---------------------------------------------------------------------------
#pragma clang fp contract(off)

#define SRF   48000.0f
#define NYQF  21600.0f                    // fp32(48000*0.45), exact
constexpr float  TWO_PI_F  = 6.283185307179586476925286766559f;  // 0x40C90FDB
constexpr double INV_2PI_D = 0.15915494309189533576888376337251;
constexpr float  RC1 = (float)INV_2PI_D;
constexpr float  RC2 = (float)(INV_2PI_D - (double)RC1);
constexpr double INV_SR_D = 1.0 / 48000.0;
constexpr float  DD1 = (float)INV_SR_D;
constexpr float  DD2 = (float)(INV_SR_D - (double)DD1);

__device__ __forceinline__ float hsin_rev(float r) {  // sin(2*pi*r)
#if __has_builtin(__builtin_amdgcn_sinf)
    return __builtin_amdgcn_sinf(r);                  // v_sin_f32: revolutions
#else
    return __sinf(r * TWO_PI_F);
#endif
}

// Correctly-rounded t/48000 via double-float mul (== IEEE f32 divide here;
// proved: no halfway cases, err 2^-47 << 2^-33.5 boundary distance).
__device__ __forceinline__ float div48000(float t) {
    float h = t * DD1;
    float r = __builtin_fmaf(t, DD1, -h);
    float s = __builtin_fmaf(t, DD2, r);
    return h + s;
}

// sin(ph) for f32 ph: double-float reduction to revolutions (|err|<=2^-25 rev)
__device__ __forceinline__ float sin_phase(float ph) {
    float h  = ph * RC1;
    float r  = __builtin_fmaf(ph, RC1, -h);
    float s  = __builtin_fmaf(ph, RC2, r);
    float nn = __builtin_rintf(h);
    float fr = (h - nn) + s;
    return hsin_rev(fr);
}

// group-of-4 broadcast: value of lane (lane&~3)+idx  (idx=0..3 static)
template <int IDX>
__device__ __forceinline__ float grp4_bcast(float v, int lb) {
#if __has_builtin(__builtin_amdgcn_ds_swizzle)
    // BitMode: offset = (xor<<10)|(or<<5)|and ; and=0x1C clears low 2 bits
    constexpr int imm = (IDX << 5) | 0x1C;
    return __int_as_float(__builtin_amdgcn_ds_swizzle(__float_as_int(v), imm));
#else
    return __shfl(v, lb + IDX);
#endif
}

// group-of-8 broadcast: value of lane (lane&~7)
__device__ __forceinline__ float grp8_bcast0(float v, int lane) {
#if __has_builtin(__builtin_amdgcn_ds_swizzle)
    // BitMode: and=0x18 clears low 3 bits, or=0, xor=0
    return __int_as_float(__builtin_amdgcn_ds_swizzle(__float_as_int(v), 0x0018));
#else
    return __shfl(v, lane & ~7);
#endif
}

// lane-pair swap: exchange values of lanes 2m <-> 2m+1 (xor 1)
__device__ __forceinline__ float pair_swap(float v) {
#if __has_builtin(__builtin_amdgcn_ds_swizzle)
    // BitMode: xor=1, and=0x1F
    return __int_as_float(__builtin_amdgcn_ds_swizzle(__float_as_int(v), 0x041F));
#else
    return __shfl_xor(v, 1);
#endif
}

// kc[b,k] = fp32(k * fp32(sqrt(fp32(1 + fp32(inh*k^2)))))  -- np/jnp-exact
__device__ __forceinline__ float kcval(int k, float ib) {
    float kf = (float)(k + 1);
    float k2 = kf * kf;
    float m  = ib * k2;
    float s1 = 1.0f + m;
    float st = (float)sqrt((double)s1);
    return kf * st;
}

// ---- K1: f0_up[b,j] (np-exact fp32 interp) + zero-init of out --------------
__global__ void __launch_bounds__(256) k_f0up(const float* __restrict__ f0,
        float* __restrict__ f0up, float* __restrict__ out,
        int T, int n, float pf) {
    int j = blockIdx.x * 256 + threadIdx.x;
    int b = blockIdx.y;
    if (j >= n) return;
    float pos = ((float)j + 0.5f);
    pos = pos * pf;
    pos = pos - 0.5f;
    pos = fmaxf(pos, 0.0f);
    pos = fminf(pos, (float)(T - 1));
    int   i0 = (int)pos;
    int   i1 = min(i0 + 1, T - 1);
    float w  = pos - (float)i0;
    float omw = 1.0f - w;
    const float* fb = f0 + b * T;
    f0up[(size_t)b * n + j] = fb[i0] * omw + fb[i1] * w;
    out[(size_t)b * n + j]  = 0.0f;            // harness poisons out; we own it
}

// ---- K2a: per (b,k) L5 scan from f0up; L4 via lane-pair swizzle (12KB) -----
// Emits S rows: sp[0] = 0, sp[1+i] = inclusive-L5-scan[i]  (len5+1 floats).
__global__ void __launch_bounds__(256) k_scan4(const float* __restrict__ f0up,
        const float* __restrict__ inh, float* __restrict__ scanS,
        int N, int n) {
    __shared__ float lv[3008];                 // levels L5..root: 2993 floats
    const int k   = blockIdx.x;
    const int b   = blockIdx.y;
    const int tid = threadIdx.x;
    const float kc = kcval(k, inh[b]);
    const float4* f4 = (const float4*)(f0up + (size_t)b * n);
    const int len4 = n >> 4;
    const int len5 = n >> 5;

    auto l2of = [&](float4 v) -> float {
        float a0 = div48000(TWO_PI_F * (kc * v.x));
        float a1 = div48000(TWO_PI_F * (kc * v.y));
        float a2 = div48000(TWO_PI_F * (kc * v.z));
        float a3 = div48000(TWO_PI_F * (kc * v.w));
        return (a0 + a1) + (a2 + a3);
    };
    auto l4of = [&](int j) -> float {          // L4 leaf j — r14-validated DAG
        float s01 = l2of(f4[4*j])     + l2of(f4[4*j + 1]);
        float s23 = l2of(f4[4*j + 2]) + l2of(f4[4*j + 3]);
        return s01 + s23;
    };
    // Leaf: one l4of per thread per iter (r18 codegen shape, 4 loads in
    // flight); L5 formed by lane-pair swizzle. Even leaf index writes
    // lv[i>>1] = fl(L4[2i] + L4[2i+1]) — r17/r20-validated bracketing.
    // len4 even and stride 256 even => pairs never straddle the active edge.
    for (int i = tid; i < len4; i += 256) {
        float v  = l4of(i);
        float vp = pair_swap(v);
        if ((i & 1) == 0) lv[i >> 1] = v + vp;
    }
    __syncthreads();

    // upsweep L5 -> root (validated pairing/order)
    int offp = 0, lenp = len5, P = 5;
    for (int l = 6; ; ++l) {
        int lenc = lenp >> 1;
        int offc = offp + lenp;
        for (int i = tid; i < lenc; i += 256)
            lv[offc + i] = lv[offp + 2*i] + lv[offp + 2*i + 1];
        __syncthreads();
        P = l;
        if (lenc == 1) break;
        offp = offc; lenp = lenc;
    }
    // downsweep to L5 (round-5-validated formulas, offsets rebased to L5)
    for (int l = P - 1; l >= 5; --l) {
        int lenl = n >> l;
        int offl = 0;
        for (int m = 5; m < l; ++m) offl += (n >> m);
        float*       arr = lv + offl;
        const float* hi  = lv + offl + lenl;
        int lenh = n >> (l + 1);
        for (int i = tid; i < lenh; i += 256) {
            float v = hi[i];
            int e = 2*i + 2;
            if (e < lenl) arr[e] = v + arr[e];
            arr[2*i + 1] = v;
        }
        __syncthreads();
    }
    // lv[0..len5) = inclusive L5 scan; emit padded S row (r18-validated).
    float* sp = scanS + (size_t)(b * N + k) * (len5 + 1);
    if (tid == 0) sp[0] = 0.0f;
    for (int i = tid; i < len5; i += 256) sp[1 + i] = lv[i];
}

// ---- K2b: 4 lanes per 16-j group (r22 body + isolated dead-wave skip) ------
__global__ void __launch_bounds__(256) k_synth4(
        const float* __restrict__ harm, const float* __restrict__ f0up,
        const float* __restrict__ inh,  const float* __restrict__ scanS,
        float* __restrict__ out, int B, int T, int N, int n, float pf, int kpg) {
    const int tid  = threadIdx.x;
    const int b    = blockIdx.y;
    const int k0   = blockIdx.z * kpg;
    const int g    = blockIdx.x * 256 + tid;   // global lane id
    const int q    = g >> 2;                   // 16-sample group
    const int c    = g & 3;                    // quarter within group
    const int NG   = n >> 4;
    const int NG5P = (n >> 5) + 1;             // S-row length
    const int kend = min(k0 + kpg, N);
    const int kact = kend - k0;
    const bool valid = q < NG;
    const bool oddq  = (q & 1) != 0;
    const int  si    = (q >> 1) + (q & 1);     // S index this lane loads

    __shared__ float2 amps[8 * 32];            // (a0, a1-a0) x k (span 1024 j)
    __shared__ float  kcs[32];
    __shared__ float  xp[4][256];              // per-wave transpose for stores

    const float ib    = inh[b];
    const float tmaxf = (float)(T - 1);
    for (int i = tid; i < kact; i += 256) kcs[i] = kcval(k0 + i, ib);

    const int j0blk = blockIdx.x * 1024;
    int i0min;
    {
        float p = ((float)j0blk + 0.5f);
        p = p * pf; p = p - 0.5f;
        p = fmaxf(p, 0.0f); p = fminf(p, tmaxf);
        i0min = (int)p;
    }
    for (int idx = tid; idx < 8 * kact; idx += 256) {
        int r = idx / kact, kk = idx - r * kact;
        int r0 = min(i0min + r, T - 1);
        int r1 = min(i0min + r + 1, T - 1);
        float a0 = harm[((size_t)b * T + r0) * N + (k0 + kk)];
        float a1 = harm[((size_t)b * T + r1) * N + (k0 + kk)];
        amps[idx] = make_float2(a0, a1 - a0);  // blend = fmaf(w, d, a0)
    }
    __syncthreads();                           // last block-wide barrier

    float u0=0.f,u1=0.f,u2=0.f,u3=0.f;
    float w0=0.f,w1=0.f,w2=0.f,w3=0.f;
    int   a0o=0,a1o=0,a2o=0,a3o=0;
    float acc0=0.f, acc1=0.f, acc2=0.f, acc3=0.f;
    float um = __builtin_inff();
    if (valid) {
        const float4 v = *(const float4*)(f0up + (size_t)b * n + (size_t)q * 16 + c * 4);
        u0=v.x; u1=v.y; u2=v.z; u3=v.w;
        um = fminf(fminf(u0,u1), fminf(u2,u3));
        const int jb = q * 16 + c * 4;
        #pragma unroll
        for (int i = 0; i < 4; ++i) {
            float p = ((float)(jb + i) + 0.5f);
            p = p * pf; p = p - 0.5f;
            p = fmaxf(p, 0.0f); p = fminf(p, tmaxf);
            int i0 = (int)p;
            float wv = p - (float)i0;
            int aoo  = (i0 - i0min) * kact;
            if (i==0){w0=wv;a0o=aoo;}
            else if (i==1){w1=wv;a1o=aoo;}
            else if (i==2){w2=wv;a2o=aoo;}
            else {w3=wv;a3o=aoo;}
        }
    }
    // wave-wide min for uniform early break
    #pragma unroll
    for (int off = 32; off > 0; off >>= 1)
        um = fminf(um, __shfl_xor(um, off));
    const float umin = um;
    const int lane = tid & 63;
    const int lb   = lane & ~3;                // group base lane (fallback path)

    // Isolated dead-wave skip (r15-measured WRITE drop, now single-variable):
    // kc monotone in k => if the partition's FIRST harmonic is Nyquist-cut
    // for every sample this wave covers, every harmonic is. Wave-uniform.
    const bool alive = (kcs[0] * umin < NYQF);

    if (valid && alive) {
        const float* s4k = scanS + (size_t)(b * N + k0) * NG5P;
        float svc = s4k[si];                   // S[i] (even q) / S[i+1] (odd q)

        for (int k = k0; k < kend; ++k) {
            const int   kk = k - k0;
            const float kc = kcs[kk];
            if (kc * umin >= NYQF) break;      // wave-uniform; kc monotone in k
            const float Sv = svc;
            if (k + 1 < kend) {                // prefetch next k row
                const float* nx = s4k + NG5P;
                svc = nx[si];
                s4k = nx;
            }

            // lane-local increments (bit-exact vs ref elementwise ops)
            float x0 = div48000(TWO_PI_F * (kc * u0));
            float x1 = div48000(TWO_PI_F * (kc * u1));
            float x2 = div48000(TWO_PI_F * (kc * u2));
            float x3 = div48000(TWO_PI_F * (kc * u3));
            float L1p = x0 + x1, L1q = x2 + x3;
            float L2  = L1p + L1q;

            // group L2 partials (FP add commutative bitwise -> exact assoc)
            float s0 = grp4_bcast<0>(L2, lb);
            float s1 = grp4_bcast<1>(L2, lb);
            float s2 = grp4_bcast<2>(L2, lb);
            float s3 = grp4_bcast<3>(L2, lb);
            float t01 = s0 + s1;
            float s23 = s2 + s3;
            float L4v = t01 + s23;             // == l4of bracketing, bit-exact
            // G reconstruction (even lanes compute the deleted downsweep add):
            float G1e = Sv + L4v;              // fl(S[i] + L4[2i]) on even q
            float Gx  = grp8_bcast0(G1e, lane);// supergroup lane0's G1e
            float G0  = oddq ? Gx : Sv;
            float G1  = oddq ? Sv : G1e;

            float b1v = G0 + s0;               // s20
            float b2v = G0 + t01;              // s3v  (g0 + (L2a+L2b))
            float b3v = b2v + s2;              // s22
            float base = (c == 0) ? G0  : (c == 1) ? b1v : (c == 2) ? b2v : b3v;
            float bn   = (c == 0) ? b1v : (c == 1) ? b2v : (c == 2) ? b3v : G1;

            float ph0 = base + x0;
            float ph1 = base + L1p;
            float ph2 = ph1 + x2;
            float ph3 = bn;

            {   float t1 = kc * u0;            // same RN product as ref mask
                if (t1 < NYQF) { float sv = sin_phase(ph0);
                    float2 a = amps[a0o + kk];
                    acc0 = __builtin_fmaf(__builtin_fmaf(w0, a.y, a.x), sv, acc0); } }
            {   float t1 = kc * u1;
                if (t1 < NYQF) { float sv = sin_phase(ph1);
                    float2 a = amps[a1o + kk];
                    acc1 = __builtin_fmaf(__builtin_fmaf(w1, a.y, a.x), sv, acc1); } }
            {   float t1 = kc * u2;
                if (t1 < NYQF) { float sv = sin_phase(ph2);
                    float2 a = amps[a2o + kk];
                    acc2 = __builtin_fmaf(__builtin_fmaf(w2, a.y, a.x), sv, acc2); } }
            {   float t1 = kc * u3;
                if (t1 < NYQF) { float sv = sin_phase(ph3);
                    float2 a = amps[a3o + kk];
                    acc3 = __builtin_fmaf(__builtin_fmaf(w3, a.y, a.x), sv, acc3); } }
        }
    }

    // ---- wave-local transpose epilogue: coalesce atomics to full 64B lines.
    // Lane l owns floats 4l..4l+3 of its wave's contiguous 1KB out span; the
    // LDS bounce makes each atomic instruction cover 64 consecutive words.
    // Per-wave LDS region -> no barrier needed (lgkmcnt orders write->read).
    // Dead waves (partition fully cut) skip: they'd only add zeros.
    if (alive) {
        const int wid  = tid >> 6;
        *(float4*)&xp[wid][4 * lane] = make_float4(acc0, acc1, acc2, acc3);
        const float Nf = (float)N;
        const int jb = blockIdx.x * 1024 + wid * 256;   // wave span [jb, jb+256)
        float* ob = out + (size_t)b * n + jb;
        #pragma unroll
        for (int i = 0; i < 4; ++i) {
            float v  = xp[wid][i * 64 + lane];
            int   jj = jb + i * 64 + lane;
            if (jj < n) atomicAdd(&ob[i * 64 + lane], v / Nf);
        }
    }
}

// ---- Fallback: round-5 proven kernel (atomics, 96 KB LDS) ------------------
__global__ void __launch_bounds__(256) k_scan_synth(
        const float* __restrict__ harm, const float* __restrict__ f0up,
        const float* __restrict__ inh,  float* __restrict__ out,
        int B, int T, int N, int n, float pf) {
    extern __shared__ float lv[];
    const int k   = blockIdx.x;
    const int b   = blockIdx.y;
    const int tid = threadIdx.x;
    const float kc = kcval(k, inh[b]);
    const float* fb = f0up + (size_t)b * n;

    auto inc = [&](int j) -> float {
        float u    = fb[j];
        float inst = kc * u;
        float tt   = TWO_PI_F * inst;
        return tt / SRF;
    };

    const int len1 = n >> 1;
    {
        const float4* f4 = (const float4*)fb;
        for (int i = tid; i < (n >> 2); i += 256) {
            float4 u = f4[i];
            float a0 = (TWO_PI_F * (kc * u.x)) / SRF;
            float a1 = (TWO_PI_F * (kc * u.y)) / SRF;
            float a2 = (TWO_PI_F * (kc * u.z)) / SRF;
            float a3 = (TWO_PI_F * (kc * u.w)) / SRF;
            lv[i] = (a0 + a1) + (a2 + a3);
        }
    }
    __syncthreads();
    int offp = 0, lenp = n >> 2, P = 2;
    for (int l = 3; ; ++l) {
        int lenc = lenp >> 1;
        int offc = offp + lenp;
        for (int i = tid; i < lenc; i += 256)
            lv[offc + i] = lv[offp + 2*i] + lv[offp + 2*i + 1];
        __syncthreads();
        P = l;
        if (lenc == 1) break;
        offp = offc; lenp = lenc;
    }
    for (int l = P - 1; l >= 2; --l) {
        int lenl = n >> l;
        int offl = 0;
        for (int m = 2; m < l; ++m) offl += (n >> m);
        float*       arr = lv + offl;
        const float* hi  = lv + offl + lenl;
        int lenh = n >> (l + 1);
        for (int i = tid; i < lenh; i += 256) {
            float v = hi[i];
            int e = 2*i + 2;
            if (e < lenl) arr[e] = v + arr[e];
            arr[2*i + 1] = v;
        }
        __syncthreads();
    }
    const float* scan2 = lv;

    const float  tmaxf = (float)(T - 1);
    const float  invN  = 1.0f / (float)N;
    const float* hb    = harm + (size_t)b * T * N + k;
    float*       ob    = out + (size_t)b * n;

    auto emit = [&](int j, float ph) {
        float u    = fb[j];
        float inst = kc * u;
        if (!(inst < NYQF)) return;
        double pr = (double)ph * INV_2PI_D;
        double fr = pr - rint(pr);
        float  sv = hsin_rev((float)fr);
        float pos = ((float)j + 0.5f);
        pos = pos * pf; pos = pos - 0.5f;
        pos = fmaxf(pos, 0.0f); pos = fminf(pos, tmaxf);
        int   i0 = (int)pos;
        int   i1 = min(i0 + 1, T - 1);
        float w  = pos - (float)i0;
        float a  = hb[(size_t)i0 * N] * (1.0f - w) + hb[(size_t)i1 * N] * w;
        atomicAdd(&ob[j], (a * sv) * invN);
    };

    if (tid == 0) emit(0, inc(0));
    for (int tt = tid; tt < len1; tt += 256) {
        float s1;
        if (tt == 0)      s1 = inc(0) + inc(1);
        else if (tt & 1)  s1 = scan2[(tt - 1) >> 1];
        else              s1 = scan2[(tt >> 1) - 1] + (inc(2*tt) + inc(2*tt + 1));
        emit(2*tt + 1, s1);
        int je = 2*tt + 2;
        if (je < n) emit(je, s1 + inc(je));
    }
}

extern "C" void kernel_launch(void* const* d_in, const int* in_sizes, int n_in,
                              void* d_out, int out_size, void* d_ws, size_t ws_size,
                              hipStream_t stream) {
    const int B = in_sizes[2];                 // 16
    const int T = in_sizes[1] / B;             // 250
    const int N = in_sizes[0] / (B * T);       // 100
    const int n = out_size / B;                // 48000
    const float pf = (float)((double)T / (double)n);

    const float* harm = (const float*)d_in[0];
    const float* f0   = (const float*)d_in[1];
    const float* inh  = (const float*)d_in[2];
    float* out  = (float*)d_out;
    float* f0up = (float*)d_ws;                // B*n floats = 3.07 MB

    const int KZ  = 4;
    const int kpg = (N + KZ - 1) / KZ;         // 25
    const int NG  = n / 16;                    // 3000
    const int NG5 = n / 32;                    // 1500
    const size_t needFast = (size_t)B * n * 4 + (size_t)B * N * (NG5 + 1) * 4;
    const bool fast = (ws_size >= needFast) && (n % 32 == 0) && (kpg <= 32);

    k_f0up<<<dim3((n + 255) / 256, B), 256, 0, stream>>>(f0, f0up, out, T, n, pf);

    if (fast) {
        float* scanS = (float*)((char*)d_ws + (size_t)B * n * 4);
        k_scan4<<<dim3(N, B), 256, 0, stream>>>(f0up, inh, scanS, N, n);
        const int tiles = (NG * 4 + 255) / 256;            // 47
        k_synth4<<<dim3(tiles, B, KZ), 256, 0, stream>>>(
            harm, f0up, inh, scanS, out, B, T, N, n, pf, kpg);
    } else {
        const size_t lds_bytes = (size_t)(n / 2) * sizeof(float);  // 96 KB
        k_scan_synth<<<dim3(N, B), 256, lds_bytes, stream>>>(
            harm, f0up, inh, out, B, T, N, n, pf);
    }
}